// Round 3
// baseline (39.803 us; speedup 1.0000x reference)
//
#include <hip/hip_runtime.h>

#define NQ 11
#define NC 3
#define NANG (NC * 66)
#define BLOCK 512

struct Mat { float u00r,u00i,u01r,u01i,u10r,u10i,u11r,u11i; };

__device__ __forceinline__ Mat loadU(const float4* __restrict__ p) {
  float4 a = p[0], b = p[1];
  Mat m; m.u00r=a.x; m.u00i=a.y; m.u01r=a.z; m.u01i=a.w;
  m.u10r=b.x; m.u10i=b.y; m.u11r=b.z; m.u11i=b.w; return m;
}

// ---- 1q gate on register bit RB (4 amps/thread) ----
template<int RB>
__device__ __forceinline__ void g_reg(float (&sr)[4], float (&si)[4], const Mat& U) {
#pragma unroll
  for (int i = 0; i < 4; ++i) {
    if (i & (1 << RB)) continue;
    const int j = i | (1 << RB);
    const float r0=sr[i], q0=si[i], r1=sr[j], q1=si[j];
    sr[i]=U.u00r*r0-U.u00i*q0+U.u01r*r1-U.u01i*q1;
    si[i]=U.u00r*q0+U.u00i*r0+U.u01r*q1+U.u01i*r1;
    sr[j]=U.u10r*r0-U.u10i*q0+U.u11r*r1-U.u11i*q1;
    si[j]=U.u10r*q0+U.u10i*r0+U.u11r*q1+U.u11i*r1;
  }
}

// ---- controlled: control reg bit CB, target reg bit TB ----
template<int CB, int TB>
__device__ __forceinline__ void g_creg(float (&sr)[4], float (&si)[4], const Mat& U) {
#pragma unroll
  for (int i = 0; i < 4; ++i) {
    if (!(i & (1 << CB)) || (i & (1 << TB))) continue;
    const int j = i | (1 << TB);
    const float r0=sr[i], q0=si[i], r1=sr[j], q1=si[j];
    sr[i]=U.u00r*r0-U.u00i*q0+U.u01r*r1-U.u01i*q1;
    si[i]=U.u00r*q0+U.u00i*r0+U.u01r*q1+U.u01i*r1;
    sr[j]=U.u10r*r0-U.u10i*q0+U.u11r*r1-U.u11i*q1;
    si[j]=U.u10r*q0+U.u10i*r0+U.u11r*q1+U.u11i*r1;
  }
}

// ---- 1q (optionally per-lane controlled) on lane bit LB ----
template<int LB, bool CTRL>
__device__ __forceinline__ void g_lane(float (&sr)[4], float (&si)[4], const Mat& U,
                                       int lane, bool cv) {
  const bool low = ((lane >> LB) & 1) == 0;
  float cor = low?U.u00r:U.u11r, coi = low?U.u00i:U.u11i;
  float cpr = low?U.u01r:U.u10r, cpi = low?U.u01i:U.u10i;
  if (CTRL) { cor = cv?cor:1.f; coi = cv?coi:0.f; cpr = cv?cpr:0.f; cpi = cv?cpi:0.f; }
#pragma unroll
  for (int i = 0; i < 4; ++i) {
    const float pr = __shfl_xor(sr[i], 1 << LB, 64);
    const float pi = __shfl_xor(si[i], 1 << LB, 64);
    const float nr = cor*sr[i]-coi*si[i]+cpr*pr-cpi*pi;
    const float ni = cor*si[i]+coi*sr[i]+cpr*pi+cpi*pr;
    sr[i]=nr; si[i]=ni;
  }
}

// ---- controlled by per-lane bool, target reg bit TB ----
template<int TB>
__device__ __forceinline__ void g_clane_reg(float (&sr)[4], float (&si)[4], const Mat& U, bool cv) {
  const float c00r=cv?U.u00r:1.f, c00i=cv?U.u00i:0.f;
  const float c01r=cv?U.u01r:0.f, c01i=cv?U.u01i:0.f;
  const float c10r=cv?U.u10r:0.f, c10i=cv?U.u10i:0.f;
  const float c11r=cv?U.u11r:1.f, c11i=cv?U.u11i:0.f;
#pragma unroll
  for (int i = 0; i < 4; ++i) {
    if (i & (1 << TB)) continue;
    const int j = i | (1 << TB);
    const float r0=sr[i], q0=si[i], r1=sr[j], q1=si[j];
    sr[i]=c00r*r0-c00i*q0+c01r*r1-c01i*q1;
    si[i]=c00r*q0+c00i*r0+c01r*q1+c01i*r1;
    sr[j]=c10r*r0-c10i*q0+c11r*r1-c11i*q1;
    si[j]=c10r*q0+c10i*r0+c11r*q1+c11i*r1;
  }
}

// ---- wave-bit gate via LDS exchange. WVX: wave-index xor (4->amp b10, 2->b9, 1->b8).
// ODD: only odd register amps participate (control = reg bit0). ----
template<int WVX, bool ODD>
__device__ __forceinline__ void g_wave(float (&sr)[4], float (&si)[4], const Mat& U,
                                       float2* __restrict__ buf, int wave, int lane, bool active) {
  const int base = (wave << 6) | lane;
  if (active) {
#pragma unroll
    for (int i = 0; i < 4; ++i) {
      if (ODD && !(i & 1)) continue;
      buf[(i << 9) | base] = make_float2(sr[i], si[i]);
    }
  }
  __syncthreads();
  if (active) {
    const int pbase = ((wave ^ WVX) << 6) | lane;
    const bool bit = (wave & WVX) != 0;
    const float cor = bit?U.u11r:U.u00r, coi = bit?U.u11i:U.u00i;
    const float cpr = bit?U.u10r:U.u01r, cpi = bit?U.u10i:U.u01i;
#pragma unroll
    for (int i = 0; i < 4; ++i) {
      if (ODD && !(i & 1)) continue;
      const float2 p = buf[(i << 9) | pbase];
      const float nr = cor*sr[i]-coi*si[i]+cpr*p.x-cpi*p.y;
      const float ni = cor*si[i]+coi*sr[i]+cpr*p.y+cpi*p.x;
      sr[i]=nr; si[i]=ni;
    }
  }
}

__global__ __launch_bounds__(BLOCK) void qsim_kernel(
    const float* __restrict__ x, const float* __restrict__ W,
    const float* __restrict__ bias, float* __restrict__ out) {
  const int bidx = blockIdx.x;
  const int tid = threadIdx.x;
  const int lane = tid & 63, wave = tid >> 6;   // wave 0..7

  __shared__ float xs[NQ];
  __shared__ float ang[NANG];
  __shared__ float4 m1[NC * NQ * 2];
  __shared__ float4 m2[NC * NQ * 2];
  __shared__ float2 ex0[2048];
  __shared__ float2 ex1[2048];
  __shared__ float red[8][22];

  if (tid < NQ) xs[tid] = x[bidx * NQ + tid];
  __syncthreads();

  if (tid < NANG) {
    const int c = tid / 66, o = tid - c * 66;
    const float* wr = W + (c * 66 + o) * NQ;
    float s = bias[c * 66 + o];
#pragma unroll
    for (int i = 0; i < NQ; ++i) s += wr[i] * xs[i];
    ang[tid] = s;
  }
  __syncthreads();

  if (tid < 2 * NC * NQ) {
    const int kind = tid / (NC * NQ);
    const int id = tid - kind * (NC * NQ);
    const int c = id / NQ, q = id - c * NQ;
    const float* a = ang + c * 66;
    if (kind == 0) {
      // U = RZ(a3) RY(a2) RZ(a1) RY(a0)
      float s0, c0, s1, c1, s2, c2, s3, c3;
      sincosf(0.5f * a[q],      &s0, &c0);
      sincosf(0.5f * a[11 + q], &s1, &c1);
      sincosf(0.5f * a[22 + q], &s2, &c2);
      sincosf(0.5f * a[33 + q], &s3, &c3);
      float m00r = c1 * c0, m00i = -s1 * c0;
      float m01r = -c1 * s0, m01i = s1 * s0;
      float m10r = c1 * s0, m10i = s1 * s0;
      float m11r = c1 * c0, m11i = s1 * c0;
      float n00r = c2 * m00r - s2 * m10r, n00i = c2 * m00i - s2 * m10i;
      float n01r = c2 * m01r - s2 * m11r, n01i = c2 * m01i - s2 * m11i;
      float n10r = s2 * m00r + c2 * m10r, n10i = s2 * m00i + c2 * m10i;
      float n11r = s2 * m01r + c2 * m11r, n11i = s2 * m01i + c2 * m11i;
      m1[id * 2 + 0] = make_float4(c3 * n00r + s3 * n00i, c3 * n00i - s3 * n00r,
                                   c3 * n01r + s3 * n01i, c3 * n01i - s3 * n01r);
      m1[id * 2 + 1] = make_float4(c3 * n10r - s3 * n10i, c3 * n10i + s3 * n10r,
                                   c3 * n11r - s3 * n11i, c3 * n11i + s3 * n11r);
    } else {
      // U = RZ(a5) RY(a4)
      float s4, c4, s5, c5;
      sincosf(0.5f * a[44 + q], &s4, &c4);
      sincosf(0.5f * a[55 + q], &s5, &c5);
      m2[id * 2 + 0] = make_float4(c5 * c4, -s5 * c4, -c5 * s4, s5 * s4);
      m2[id * 2 + 1] = make_float4(c5 * s4,  s5 * s4,  c5 * c4, s5 * c4);
    }
  }
  __syncthreads();

  // state: amp bits [1:0]=reg, [7:2]=lane, [10:8]=wave ; qubit q <-> bit 10-q
  float sr[4], si[4];
#pragma unroll
  for (int i = 0; i < 4; ++i) { sr[i] = 0.f; si[i] = 0.f; }
  if (tid == 0) sr[0] = 1.f;

  for (int c = 0; c < NC; ++c) {
    const float4* M1 = &m1[c * NQ * 2];
    const float4* M2 = &m2[c * NQ * 2];
    // ---- single-qubit layer ----
    g_wave<4,false>(sr, si, loadU(M1 + 0 * 2), ex0, wave, lane, true);  // q0: b10
    g_wave<2,false>(sr, si, loadU(M1 + 1 * 2), ex1, wave, lane, true);  // q1: b9
    g_wave<1,false>(sr, si, loadU(M1 + 2 * 2), ex0, wave, lane, true);  // q2: b8
    g_lane<5,false>(sr, si, loadU(M1 + 3 * 2), lane, false);            // q3: b7
    g_lane<4,false>(sr, si, loadU(M1 + 4 * 2), lane, false);
    g_lane<3,false>(sr, si, loadU(M1 + 5 * 2), lane, false);
    g_lane<2,false>(sr, si, loadU(M1 + 6 * 2), lane, false);
    g_lane<1,false>(sr, si, loadU(M1 + 7 * 2), lane, false);
    g_lane<0,false>(sr, si, loadU(M1 + 8 * 2), lane, false);            // q8: b2
    g_reg<1>(sr, si, loadU(M1 + 9 * 2));                                // q9: b1
    g_reg<0>(sr, si, loadU(M1 + 10 * 2));                               // q10: b0
    // ---- controlled layer: control b(10-q), target b(10-(q+1)%11) ----
    g_wave<2,false>(sr, si, loadU(M2 + 0 * 2), ex1, wave, lane, (wave & 4) != 0); // q0
    g_wave<1,false>(sr, si, loadU(M2 + 1 * 2), ex0, wave, lane, (wave & 2) != 0); // q1
    if (wave & 1) g_lane<5,false>(sr, si, loadU(M2 + 2 * 2), lane, false);        // q2 (ctrl wave-uniform)
    g_lane<4,true >(sr, si, loadU(M2 + 3 * 2), lane, (lane & 32) != 0);           // q3
    g_lane<3,true >(sr, si, loadU(M2 + 4 * 2), lane, (lane & 16) != 0);           // q4
    g_lane<2,true >(sr, si, loadU(M2 + 5 * 2), lane, (lane & 8) != 0);            // q5
    g_lane<1,true >(sr, si, loadU(M2 + 6 * 2), lane, (lane & 4) != 0);            // q6
    g_lane<0,true >(sr, si, loadU(M2 + 7 * 2), lane, (lane & 2) != 0);            // q7
    g_clane_reg<1>(sr, si, loadU(M2 + 8 * 2), (lane & 1) != 0);                   // q8
    g_creg<1,0>(sr, si, loadU(M2 + 9 * 2));                                       // q9
    g_wave<4,true >(sr, si, loadU(M2 + 10 * 2), ex1, wave, lane, true);           // q10 (ODD)
  }

  // ---- expectations ----
  const int base = (wave << 6) | lane;
#pragma unroll
  for (int i = 0; i < 4; ++i) ex0[(i << 9) | base] = make_float2(sr[i], si[i]);
  __syncthreads();
  const int pb4 = ((wave ^ 4) << 6) | lane;
  const int pb2 = ((wave ^ 2) << 6) | lane;
  const int pb1 = ((wave ^ 1) << 6) | lane;
  float xw4 = 0.f, xw2 = 0.f, xw1 = 0.f;
#pragma unroll
  for (int i = 0; i < 4; ++i) {
    const float2 p4 = ex0[(i << 9) | pb4];
    const float2 p2 = ex0[(i << 9) | pb2];
    const float2 p1 = ex0[(i << 9) | pb1];
    xw4 += sr[i] * p4.x + si[i] * p4.y;
    xw2 += sr[i] * p2.x + si[i] * p2.y;
    xw1 += sr[i] * p1.x + si[i] * p1.y;
  }
  float mg[4];
#pragma unroll
  for (int i = 0; i < 4; ++i) mg[i] = sr[i] * sr[i] + si[i] * si[i];
  const float ztot = (mg[0] + mg[1]) + (mg[2] + mg[3]);
  const float zr1 = (mg[0] + mg[1]) - (mg[2] + mg[3]);   // Z q9 (bit1)
  const float zr0 = (mg[0] - mg[1]) + (mg[2] - mg[3]);   // Z q10 (bit0)
  float xr1 = 0.f, xr0 = 0.f;
#pragma unroll
  for (int i = 0; i < 4; ++i) {
    xr1 += sr[i] * sr[i ^ 2] + si[i] * si[i ^ 2];        // X q9
    xr0 += sr[i] * sr[i ^ 1] + si[i] * si[i ^ 1];        // X q10
  }
  float xl5=0.f, xl4=0.f, xl3=0.f, xl2=0.f, xl1=0.f, xl0=0.f;
#pragma unroll
  for (int i = 0; i < 4; ++i) {
    xl5 += sr[i]*__shfl_xor(sr[i], 32, 64) + si[i]*__shfl_xor(si[i], 32, 64);
    xl4 += sr[i]*__shfl_xor(sr[i], 16, 64) + si[i]*__shfl_xor(si[i], 16, 64);
    xl3 += sr[i]*__shfl_xor(sr[i], 8, 64)  + si[i]*__shfl_xor(si[i], 8, 64);
    xl2 += sr[i]*__shfl_xor(sr[i], 4, 64)  + si[i]*__shfl_xor(si[i], 4, 64);
    xl1 += sr[i]*__shfl_xor(sr[i], 2, 64)  + si[i]*__shfl_xor(si[i], 2, 64);
    xl0 += sr[i]*__shfl_xor(sr[i], 1, 64)  + si[i]*__shfl_xor(si[i], 1, 64);
  }

  float v[22];
  v[0] = xw4; v[1] = xw2; v[2] = xw1;                 // X q0,q1,q2
  v[3]=xl5; v[4]=xl4; v[5]=xl3; v[6]=xl2; v[7]=xl1; v[8]=xl0; // X q3..q8
  v[9]=xr1; v[10]=xr0;                                // X q9,q10
  v[11] = (wave & 4) ? -ztot : ztot;                  // Z q0
  v[12] = (wave & 2) ? -ztot : ztot;                  // Z q1
  v[13] = (wave & 1) ? -ztot : ztot;                  // Z q2
  v[14] = (lane & 32) ? -ztot : ztot;                 // Z q3
  v[15] = (lane & 16) ? -ztot : ztot;
  v[16] = (lane & 8)  ? -ztot : ztot;
  v[17] = (lane & 4)  ? -ztot : ztot;
  v[18] = (lane & 2)  ? -ztot : ztot;
  v[19] = (lane & 1)  ? -ztot : ztot;                 // Z q8
  v[20] = zr1; v[21] = zr0;                           // Z q9,q10
#pragma unroll
  for (int k = 0; k < 22; ++k) {
#pragma unroll
    for (int off = 32; off; off >>= 1) v[k] += __shfl_xor(v[k], off, 64);
  }
  if (lane == 0) {
#pragma unroll
    for (int k = 0; k < 22; ++k) red[wave][k] = v[k];
  }
  __syncthreads();
  if (tid < 22) {
    float s = 0.f;
#pragma unroll
    for (int w = 0; w < 8; ++w) s += red[w][tid];
    out[bidx * 22 + tid] = s;
  }
}

extern "C" void kernel_launch(void* const* d_in, const int* in_sizes, int n_in,
                              void* d_out, int out_size, void* d_ws, size_t ws_size,
                              hipStream_t stream) {
  (void)n_in; (void)d_ws; (void)ws_size; (void)out_size;
  const float* x = (const float*)d_in[0];
  const float* W = (const float*)d_in[1];
  const float* b = (const float*)d_in[2];
  float* out = (float*)d_out;
  const int batch = in_sizes[0] / NQ;
  qsim_kernel<<<batch, BLOCK, 0, stream>>>(x, W, b, out);
}

// Round 4
// 27.057 us; speedup vs baseline: 1.4711x; 1.4711x over previous
//
#include <hip/hip_runtime.h>

#define NQ 11
#define NC 3
#define NANG (NC * 66)
#define BLOCK 512

struct Mat { float u00r,u00i,u01r,u01i,u10r,u10i,u11r,u11i; };

__device__ __forceinline__ Mat loadU(const float4* p) {
  float4 a = p[0], b = p[1];
  Mat m; m.u00r=a.x; m.u00i=a.y; m.u01r=a.z; m.u01i=a.w;
  m.u10r=b.x; m.u10i=b.y; m.u11r=b.z; m.u11i=b.w; return m;
}

// DPP cross-lane: quad_perm. 0xB1 = xor1, 0x4E = xor2.
template<int CTRL>
__device__ __forceinline__ float dppx(float v) {
  return __int_as_float(__builtin_amdgcn_update_dpp(
      0, __float_as_int(v), CTRL, 0xF, 0xF, false));
}

// apply 2x2 complex U to amplitude pair
__device__ __forceinline__ void apply2(float& r0, float& i0, float& r1, float& i1, const Mat& U) {
  const float a=r0,b=i0,c=r1,d=i1;
  r0 = U.u00r*a - U.u00i*b + U.u01r*c - U.u01i*d;
  i0 = U.u00r*b + U.u00i*a + U.u01r*d + U.u01i*c;
  r1 = U.u10r*a - U.u10i*b + U.u11r*c - U.u11i*d;
  i1 = U.u10r*b + U.u10i*a + U.u11r*d + U.u11i*c;
}

// gate on lane bit MASK via shfl (V already control-selected per thread)
template<int MASK>
__device__ __forceinline__ void g_lane_shfl(float (&sr)[4], float (&si)[4], const Mat& U, int lane) {
  const bool hi = (lane & MASK) != 0;
  const float cor = hi?U.u11r:U.u00r, coi = hi?U.u11i:U.u00i;
  const float cpr = hi?U.u10r:U.u01r, cpi = hi?U.u10i:U.u01i;
#pragma unroll
  for (int i = 0; i < 4; ++i) {
    const float pr = __shfl_xor(sr[i], MASK, 64);
    const float pi = __shfl_xor(si[i], MASK, 64);
    const float nr = cor*sr[i]-coi*si[i]+cpr*pr-cpi*pi;
    const float ni = cor*si[i]+coi*sr[i]+cpr*pi+cpi*pr;
    sr[i]=nr; si[i]=ni;
  }
}

// gate on lane bit MASK (1 or 2) via DPP quad_perm (VALU pipe, no DS)
template<int CTRL, int MASK>
__device__ __forceinline__ void g_lane_dpp(float (&sr)[4], float (&si)[4], const Mat& U, int lane) {
  const bool hi = (lane & MASK) != 0;
  const float cor = hi?U.u11r:U.u00r, coi = hi?U.u11i:U.u00i;
  const float cpr = hi?U.u10r:U.u01r, cpi = hi?U.u10i:U.u01i;
#pragma unroll
  for (int i = 0; i < 4; ++i) {
    const float pr = dppx<CTRL>(sr[i]);
    const float pi = dppx<CTRL>(si[i]);
    const float nr = cor*sr[i]-coi*si[i]+cpr*pr-cpi*pi;
    const float ni = cor*si[i]+coi*sr[i]+cpr*pi+cpi*pr;
    sr[i]=nr; si[i]=ni;
  }
}

// gate on reg bit1 (pairs (0,2),(1,3)); V pre-selected per thread
__device__ __forceinline__ void g_reg_b1(float (&sr)[4], float (&si)[4], const Mat& U) {
  apply2(sr[0], si[0], sr[2], si[2], U);
  apply2(sr[1], si[1], sr[3], si[3], U);
}

// full 1q gate on wave bit (wave xor WVX), all 4 amps through LDS
template<int WVX>
__device__ __forceinline__ void g_wave_full(float (&sr)[4], float (&si)[4], const Mat& U,
                                            float2* buf, int wave, int lane) {
  const int base = (wave << 6) | lane;
#pragma unroll
  for (int i = 0; i < 4; ++i) buf[(i << 9) | base] = make_float2(sr[i], si[i]);
  __syncthreads();
  const int pbase = ((wave ^ WVX) << 6) | lane;
  const bool bit = (wave & WVX) != 0;
  const float cor = bit?U.u11r:U.u00r, coi = bit?U.u11i:U.u00i;
  const float cpr = bit?U.u10r:U.u01r, cpi = bit?U.u10i:U.u01i;
#pragma unroll
  for (int i = 0; i < 4; ++i) {
    const float2 p = buf[(i << 9) | pbase];
    const float nr = cor*sr[i]-coi*si[i]+cpr*p.x-cpi*p.y;
    const float ni = cor*si[i]+coi*sr[i]+cpr*p.y+cpi*p.x;
    sr[i]=nr; si[i]=ni;
  }
}

// controlled gate, ctrl = reg bit0 (amps 1,3), target wave bit
template<int WVX>
__device__ __forceinline__ void g_wave_half(float (&sr)[4], float (&si)[4], const Mat& U,
                                            float2* buf, int wave, int lane) {
  const int base = (wave << 6) | lane;
  buf[(1 << 9) | base] = make_float2(sr[1], si[1]);
  buf[(3 << 9) | base] = make_float2(sr[3], si[3]);
  __syncthreads();
  const int pbase = ((wave ^ WVX) << 6) | lane;
  const bool bit = (wave & WVX) != 0;
  const float cor = bit?U.u11r:U.u00r, coi = bit?U.u11i:U.u00i;
  const float cpr = bit?U.u10r:U.u01r, cpi = bit?U.u10i:U.u01i;
  {
    const float2 p = buf[(1 << 9) | pbase];
    const float nr = cor*sr[1]-coi*si[1]+cpr*p.x-cpi*p.y;
    const float ni = cor*si[1]+coi*sr[1]+cpr*p.y+cpi*p.x;
    sr[1]=nr; si[1]=ni;
  }
  {
    const float2 p = buf[(3 << 9) | pbase];
    const float nr = cor*sr[3]-coi*si[3]+cpr*p.x-cpi*p.y;
    const float ni = cor*si[3]+coi*sr[3]+cpr*p.y+cpi*p.x;
    sr[3]=nr; si[3]=ni;
  }
}

__global__ __launch_bounds__(BLOCK) void qsim_kernel(
    const float* __restrict__ x, const float* __restrict__ W,
    const float* __restrict__ bias, float* __restrict__ out) {
  const int bidx = blockIdx.x;
  const int tid = threadIdx.x;
  const int lane = tid & 63, wave = tid >> 6;   // wave 0..7

  __shared__ float xs[NQ];
  __shared__ float ang[NANG];
  __shared__ float4 m1s[NC * NQ * 2];   // fused 1q matrices
  __shared__ float4 m2s[NC * NQ * 2];   // fused controlled matrices
  __shared__ float4 v1s[NC * 10 * 2];   // V1[t] = m2[t-1] * m1[t], t=1..10
  __shared__ float2 ex0[2048];
  __shared__ float2 ex1[2048];
  __shared__ float red[8][24];

  if (tid < NQ) xs[tid] = x[bidx * NQ + tid];
  __syncthreads();

  if (tid < NANG) {
    const int c = tid / 66, o = tid - c * 66;
    const float* wr = W + (c * 66 + o) * NQ;
    float s = bias[c * 66 + o];
#pragma unroll
    for (int i = 0; i < NQ; ++i) s += wr[i] * xs[i];
    ang[tid] = s;
  }
  __syncthreads();

  if (tid < 2 * NC * NQ) {
    const int kind = tid / (NC * NQ);
    const int id = tid - kind * (NC * NQ);
    const int c = id / NQ, q = id - c * NQ;
    const float* a = ang + c * 66;
    if (kind == 0) {
      // U = RZ(a3) RY(a2) RZ(a1) RY(a0)
      float s0, c0, s1, c1, s2, c2, s3, c3;
      sincosf(0.5f * a[q],      &s0, &c0);
      sincosf(0.5f * a[11 + q], &s1, &c1);
      sincosf(0.5f * a[22 + q], &s2, &c2);
      sincosf(0.5f * a[33 + q], &s3, &c3);
      float m00r = c1 * c0, m00i = -s1 * c0;
      float m01r = -c1 * s0, m01i = s1 * s0;
      float m10r = c1 * s0, m10i = s1 * s0;
      float m11r = c1 * c0, m11i = s1 * c0;
      float n00r = c2 * m00r - s2 * m10r, n00i = c2 * m00i - s2 * m10i;
      float n01r = c2 * m01r - s2 * m11r, n01i = c2 * m01i - s2 * m11i;
      float n10r = s2 * m00r + c2 * m10r, n10i = s2 * m00i + c2 * m10i;
      float n11r = s2 * m01r + c2 * m11r, n11i = s2 * m01i + c2 * m11i;
      m1s[id * 2 + 0] = make_float4(c3 * n00r + s3 * n00i, c3 * n00i - s3 * n00r,
                                    c3 * n01r + s3 * n01i, c3 * n01i - s3 * n01r);
      m1s[id * 2 + 1] = make_float4(c3 * n10r - s3 * n10i, c3 * n10i + s3 * n10r,
                                    c3 * n11r - s3 * n11i, c3 * n11i + s3 * n11r);
    } else {
      // U = RZ(a5) RY(a4)
      float s4, c4, s5, c5;
      sincosf(0.5f * a[44 + q], &s4, &c4);
      sincosf(0.5f * a[55 + q], &s5, &c5);
      m2s[id * 2 + 0] = make_float4(c5 * c4, -s5 * c4, -c5 * s4, s5 * s4);
      m2s[id * 2 + 1] = make_float4(c5 * s4,  s5 * s4,  c5 * c4, s5 * c4);
    }
  }
  __syncthreads();

  // fused products V1[c][t] = m2[c][t-1] * m1[c][t], t=1..10
  if (tid < NC * 10) {
    const int c = tid / 10, tt = tid - c * 10, t = tt + 1;
    const Mat A = loadU(&m2s[(c * NQ + t - 1) * 2]);
    const Mat B = loadU(&m1s[(c * NQ + t) * 2]);
    float c00r = A.u00r*B.u00r - A.u00i*B.u00i + A.u01r*B.u10r - A.u01i*B.u10i;
    float c00i = A.u00r*B.u00i + A.u00i*B.u00r + A.u01r*B.u10i + A.u01i*B.u10r;
    float c01r = A.u00r*B.u01r - A.u00i*B.u01i + A.u01r*B.u11r - A.u01i*B.u11i;
    float c01i = A.u00r*B.u01i + A.u00i*B.u01r + A.u01r*B.u11i + A.u01i*B.u11r;
    float c10r = A.u10r*B.u00r - A.u10i*B.u00i + A.u11r*B.u10r - A.u11i*B.u10i;
    float c10i = A.u10r*B.u00i + A.u10i*B.u00r + A.u11r*B.u10i + A.u11i*B.u10r;
    float c11r = A.u10r*B.u01r - A.u10i*B.u01i + A.u11r*B.u11r - A.u11i*B.u11i;
    float c11i = A.u10r*B.u01i + A.u10i*B.u01r + A.u11r*B.u11i + A.u11i*B.u11r;
    v1s[(c * 10 + tt) * 2 + 0] = make_float4(c00r, c00i, c01r, c01i);
    v1s[(c * 10 + tt) * 2 + 1] = make_float4(c10r, c10i, c11r, c11i);
  }
  __syncthreads();

  // state: amp bits [1:0]=reg, [7:2]=lane, [10:8]=wave ; qubit q <-> bit 10-q
  float sr[4], si[4];
#pragma unroll
  for (int i = 0; i < 4; ++i) { sr[i] = 0.f; si[i] = 0.f; }
  if (tid == 0) sr[0] = 1.f;

  // schedule per circuit: 1q(0); F(t|t-1) for t=1..10 (V = ctrl ? m2[t-1]*m1[t] : m1[t]);
  // C(10->0). Valid: 1q(t) commutes past C(j->j+1) for j < t-1.
  for (int c = 0; c < NC; ++c) {
    const float4* M1 = &m1s[c * NQ * 2];
    const float4* M2 = &m2s[c * NQ * 2];
    const float4* VF = &v1s[c * 10 * 2];
    g_wave_full<4>(sr, si, loadU(M1 + 0 * 2), ex0, wave, lane);                    // e0: 1q(0) @w2
    g_wave_full<2>(sr, si, loadU((wave & 4) ? VF + 0*2 : M1 + 1*2), ex1, wave, lane); // e1: F(1|0)
    g_wave_full<1>(sr, si, loadU((wave & 2) ? VF + 1*2 : M1 + 2*2), ex0, wave, lane); // e2: F(2|1)
    g_lane_shfl<32>(sr, si, loadU((wave & 1) ? VF + 2*2 : M1 + 3*2), lane);        // e3: F(3|2)
    g_lane_shfl<16>(sr, si, loadU((lane & 32) ? VF + 3*2 : M1 + 4*2), lane);       // e4: F(4|3)
    g_lane_shfl<8> (sr, si, loadU((lane & 16) ? VF + 4*2 : M1 + 5*2), lane);       // e5: F(5|4)
    g_lane_shfl<4> (sr, si, loadU((lane & 8)  ? VF + 5*2 : M1 + 6*2), lane);       // e6: F(6|5)
    g_lane_dpp<0x4E,2>(sr, si, loadU((lane & 4) ? VF + 6*2 : M1 + 7*2), lane);     // e7: F(7|6)
    g_lane_dpp<0xB1,1>(sr, si, loadU((lane & 2) ? VF + 7*2 : M1 + 8*2), lane);     // e8: F(8|7)
    g_reg_b1(sr, si, loadU((lane & 1) ? VF + 8*2 : M1 + 9*2));                     // e9: F(9|8)
    {                                                                               // e10: F(10|9)
      const Mat V0 = loadU(M1 + 10 * 2);
      const Mat Vc = loadU(VF + 9 * 2);
      apply2(sr[0], si[0], sr[1], si[1], V0);   // amps bit1=0: ctrl q9=0
      apply2(sr[2], si[2], sr[3], si[3], Vc);   // amps bit1=1: ctrl q9=1
    }
    g_wave_half<4>(sr, si, loadU(M2 + 10 * 2), ex1, wave, lane);                   // e11: C(10->0)
  }

  // ---- expectations ----
  const int base = (wave << 6) | lane;
#pragma unroll
  for (int i = 0; i < 4; ++i) ex0[(i << 9) | base] = make_float2(sr[i], si[i]);
  __syncthreads();
  const int pb4 = ((wave ^ 4) << 6) | lane;
  const int pb2 = ((wave ^ 2) << 6) | lane;
  const int pb1 = ((wave ^ 1) << 6) | lane;
  float xw4 = 0.f, xw2 = 0.f, xw1 = 0.f;
#pragma unroll
  for (int i = 0; i < 4; ++i) {
    const float2 p4 = ex0[(i << 9) | pb4];
    const float2 p2 = ex0[(i << 9) | pb2];
    const float2 p1 = ex0[(i << 9) | pb1];
    xw4 += sr[i] * p4.x + si[i] * p4.y;
    xw2 += sr[i] * p2.x + si[i] * p2.y;
    xw1 += sr[i] * p1.x + si[i] * p1.y;
  }
  float mg[4];
#pragma unroll
  for (int i = 0; i < 4; ++i) mg[i] = sr[i] * sr[i] + si[i] * si[i];
  const float ztot = (mg[0] + mg[1]) + (mg[2] + mg[3]);
  const float zr1 = (mg[0] + mg[1]) - (mg[2] + mg[3]);   // Z q9
  const float zr0 = (mg[0] - mg[1]) + (mg[2] - mg[3]);   // Z q10
  float xr1 = 0.f, xr0 = 0.f;
#pragma unroll
  for (int i = 0; i < 4; ++i) {
    xr1 += sr[i] * sr[i ^ 2] + si[i] * si[i ^ 2];        // X q9
    xr0 += sr[i] * sr[i ^ 1] + si[i] * si[i ^ 1];        // X q10
  }
  float xl5=0.f, xl4=0.f, xl3=0.f, xl2=0.f, xl1=0.f, xl0=0.f;
#pragma unroll
  for (int i = 0; i < 4; ++i) {
    xl5 += sr[i]*__shfl_xor(sr[i], 32, 64) + si[i]*__shfl_xor(si[i], 32, 64);
    xl4 += sr[i]*__shfl_xor(sr[i], 16, 64) + si[i]*__shfl_xor(si[i], 16, 64);
    xl3 += sr[i]*__shfl_xor(sr[i], 8, 64)  + si[i]*__shfl_xor(si[i], 8, 64);
    xl2 += sr[i]*__shfl_xor(sr[i], 4, 64)  + si[i]*__shfl_xor(si[i], 4, 64);
    xl1 += sr[i]*dppx<0x4E>(sr[i]) + si[i]*dppx<0x4E>(si[i]);
    xl0 += sr[i]*dppx<0xB1>(sr[i]) + si[i]*dppx<0xB1>(si[i]);
  }

  float v[22];
  v[0] = xw4; v[1] = xw2; v[2] = xw1;
  v[3]=xl5; v[4]=xl4; v[5]=xl3; v[6]=xl2; v[7]=xl1; v[8]=xl0;
  v[9]=xr1; v[10]=xr0;
  v[11] = (wave & 4) ? -ztot : ztot;
  v[12] = (wave & 2) ? -ztot : ztot;
  v[13] = (wave & 1) ? -ztot : ztot;
  v[14] = (lane & 32) ? -ztot : ztot;
  v[15] = (lane & 16) ? -ztot : ztot;
  v[16] = (lane & 8)  ? -ztot : ztot;
  v[17] = (lane & 4)  ? -ztot : ztot;
  v[18] = (lane & 2)  ? -ztot : ztot;
  v[19] = (lane & 1)  ? -ztot : ztot;
  v[20] = zr1; v[21] = zr0;

  // quad-level reduce on VALU (DPP), then pack 4 observables/register for the
  // remaining 4 shuffle levels: 44 DPP + 24 shfl instead of 132 shfl.
#pragma unroll
  for (int k = 0; k < 22; ++k) {
    v[k] += dppx<0xB1>(v[k]);
    v[k] += dppx<0x4E>(v[k]);
  }
  const int q4 = lane & 3;
  float wv[6];
#pragma unroll
  for (int p = 0; p < 5; ++p) {
    wv[p] = q4 == 0 ? v[4*p] : (q4 == 1 ? v[4*p+1] : (q4 == 2 ? v[4*p+2] : v[4*p+3]));
  }
  wv[5] = q4 == 0 ? v[20] : (q4 == 1 ? v[21] : 0.f);
#pragma unroll
  for (int p = 0; p < 6; ++p) {
    wv[p] += __shfl_xor(wv[p], 4, 64);
    wv[p] += __shfl_xor(wv[p], 8, 64);
    wv[p] += __shfl_xor(wv[p], 16, 64);
    wv[p] += __shfl_xor(wv[p], 32, 64);
  }
  if (lane < 4) {
#pragma unroll
    for (int p = 0; p < 6; ++p) red[wave][4*p + lane] = wv[p];
  }
  __syncthreads();
  if (tid < 22) {
    float s = 0.f;
#pragma unroll
    for (int w8 = 0; w8 < 8; ++w8) s += red[w8][tid];
    out[bidx * 22 + tid] = s;
  }
}

extern "C" void kernel_launch(void* const* d_in, const int* in_sizes, int n_in,
                              void* d_out, int out_size, void* d_ws, size_t ws_size,
                              hipStream_t stream) {
  (void)n_in; (void)d_ws; (void)ws_size; (void)out_size;
  const float* x = (const float*)d_in[0];
  const float* W = (const float*)d_in[1];
  const float* b = (const float*)d_in[2];
  float* out = (float*)d_out;
  const int batch = in_sizes[0] / NQ;
  qsim_kernel<<<batch, BLOCK, 0, stream>>>(x, W, b, out);
}

// Round 5
// 26.529 us; speedup vs baseline: 1.5004x; 1.0199x over previous
//
#include <hip/hip_runtime.h>

#define NQ 11
#define NC 3
#define NANG (NC * 66)
#define BLOCK 512

typedef int i32x2 __attribute__((ext_vector_type(2)));

// DPP quad_perm: 0xB1 = xor1, 0x4E = xor2
template<int CTRL>
__device__ __forceinline__ float dppx(float v) {
  return __int_as_float(__builtin_amdgcn_update_dpp(
      0, __float_as_int(v), CTRL, 0xF, 0xF, false));
}

// partner value at lane^16 / lane^32 via gfx950 permlane swaps (VALU pipe)
__device__ __forceinline__ float plp16(float v, int lane) {
  auto r = __builtin_amdgcn_permlane16_swap(__float_as_int(v), __float_as_int(v), false, false);
  return __int_as_float((lane & 16) ? r[0] : r[1]);
}
__device__ __forceinline__ float plp32(float v, int lane) {
  auto r = __builtin_amdgcn_permlane32_swap(__float_as_int(v), __float_as_int(v), false, false);
  return __int_as_float((lane & 32) ? r[0] : r[1]);
}
// own + partner (semantics-proof: {r0,r1} = {own,partner} as a set)
__device__ __forceinline__ float plsum16(float v) {
  auto r = __builtin_amdgcn_permlane16_swap(__float_as_int(v), __float_as_int(v), false, false);
  return __int_as_float(r[0]) + __int_as_float(r[1]);
}
__device__ __forceinline__ float plsum32(float v) {
  auto r = __builtin_amdgcn_permlane32_swap(__float_as_int(v), __float_as_int(v), false, false);
  return __int_as_float(r[0]) + __int_as_float(r[1]);
}

// SU(2) matrix U = [[a, b], [-conj(b), conj(a)]] stored as float4 (ar, ai, br, bi).
// Apply to in-thread pair:
__device__ __forceinline__ void apply2f(float& r0, float& i0, float& r1, float& i1, float4 U) {
  const float ar=U.x, ai=U.y, br=U.z, bi=U.w;
  const float nr0 = ar*r0 - ai*i0 + br*r1 - bi*i1;
  const float ni0 = ar*i0 + ai*r0 + br*i1 + bi*r1;
  const float nr1 = -br*r0 - bi*i0 + ar*r1 + ai*i1;
  const float ni1 = -br*i0 + bi*r0 + ar*i1 - ai*r1;
  r0=nr0; i0=ni0; r1=nr1; i1=ni1;
}
// own/partner form with row select (hi: row1 coeffs conj(a), -conj(b))
__device__ __forceinline__ void gpart(float& r, float& i, float pr, float pi, float4 U, bool hi) {
  const float cor = U.x;
  const float coi = hi ? -U.y : U.y;
  const float cpr = hi ? -U.z : U.z;
  const float cpi = U.w;
  const float nr = cor*r - coi*i + cpr*pr - cpi*pi;
  const float ni = cor*i + coi*r + cpr*pi + cpi*pr;
  r = nr; i = ni;
}

template<int M>
__device__ __forceinline__ void g_shfl(float (&sr)[4], float (&si)[4], float4 U, int lane) {
  const bool hi = (lane & M) != 0;
#pragma unroll
  for (int i = 0; i < 4; ++i) {
    const float pr = __shfl_xor(sr[i], M, 64);
    const float pi = __shfl_xor(si[i], M, 64);
    gpart(sr[i], si[i], pr, pi, U, hi);
  }
}
template<int CTRL, int M>
__device__ __forceinline__ void g_dpp(float (&sr)[4], float (&si)[4], float4 U, int lane) {
  const bool hi = (lane & M) != 0;
#pragma unroll
  for (int i = 0; i < 4; ++i) {
    const float pr = dppx<CTRL>(sr[i]);
    const float pi = dppx<CTRL>(si[i]);
    gpart(sr[i], si[i], pr, pi, U, hi);
  }
}
__device__ __forceinline__ void g_pl16(float (&sr)[4], float (&si)[4], float4 U, int lane) {
  const bool hi = (lane & 16) != 0;
#pragma unroll
  for (int i = 0; i < 4; ++i) {
    const float pr = plp16(sr[i], lane);
    const float pi = plp16(si[i], lane);
    gpart(sr[i], si[i], pr, pi, U, hi);
  }
}
// target lane bit 32; matrix selected per amp by reg bit0 (U0: bit0=0, U1: bit0=1)
__device__ __forceinline__ void g_pl32_regsel(float (&sr)[4], float (&si)[4], float4 U0, float4 U1, int lane) {
  const bool hi = (lane & 32) != 0;
#pragma unroll
  for (int i = 0; i < 4; ++i) {
    const float pr = plp32(sr[i], lane);
    const float pi = plp32(si[i], lane);
    gpart(sr[i], si[i], pr, pi, (i & 1) ? U1 : U0, hi);
  }
}
// wave-bit gate via LDS exchange (write, barrier, read)
template<int WVX>
__device__ __forceinline__ void g_wave(float (&sr)[4], float (&si)[4], float4 U,
                                       float2* buf, int wave, int lane) {
  const int base = (wave << 6) | lane;
#pragma unroll
  for (int i = 0; i < 4; ++i) buf[(i << 9) | base] = make_float2(sr[i], si[i]);
  __syncthreads();
  const int pbase = ((wave ^ WVX) << 6) | lane;
  const bool hi = (wave & WVX) != 0;
#pragma unroll
  for (int i = 0; i < 4; ++i) {
    const float2 p = buf[(i << 9) | pbase];
    gpart(sr[i], si[i], p.x, p.y, U, hi);
  }
}

__global__ __launch_bounds__(BLOCK) void qsim_kernel(
    const float* __restrict__ x, const float* __restrict__ W,
    const float* __restrict__ bias, float* __restrict__ out) {
  const int bidx = blockIdx.x;
  const int tid = threadIdx.x;
  const int lane = tid & 63, wave = tid >> 6;   // wave 0..7

  __shared__ float xs[NQ];
  __shared__ float ang[NANG];
  __shared__ float4 m1s[NC * NQ];   // fused 1q matrices (SU2)
  __shared__ float4 m2s[NC * NQ];   // fused controlled matrices (SU2)
  __shared__ float4 v1s[NC * 10];   // V[t] = m2[t-1] * m1[t], t=1..10
  __shared__ float2 ex0[2048];
  __shared__ float2 ex1[2048];
  __shared__ float red[8][24];

  if (tid < NQ) xs[tid] = x[bidx * NQ + tid];
  __syncthreads();

  if (tid < NANG) {
    const int c = tid / 66, o = tid - c * 66;
    const float* wr = W + (c * 66 + o) * NQ;
    float s = bias[c * 66 + o];
#pragma unroll
    for (int i = 0; i < NQ; ++i) s += wr[i] * xs[i];
    ang[tid] = s;
  }
  __syncthreads();

  if (tid < 2 * NC * NQ) {
    const int kind = tid / (NC * NQ);
    const int id = tid - kind * (NC * NQ);
    const int c = id / NQ, q = id - c * NQ;
    const float* a = ang + c * 66;
    if (kind == 0) {
      // U = RZ(a3) RY(a2) RZ(a1) RY(a0), SU2 form (a,b)
      float s0,c0,s1,c1,s2,c2,s3,c3;
      sincosf(0.5f*a[q],      &s0,&c0);
      sincosf(0.5f*a[11+q],   &s1,&c1);
      sincosf(0.5f*a[22+q],   &s2,&c2);
      sincosf(0.5f*a[33+q],   &s3,&c3);
      const float mar = c1*c0, mai = -s1*c0;       // e1*c0
      const float mbr = -c1*s0, mbi = s1*s0;       // e1*(-s0)
      const float nar = c2*mar + s2*mbr, nai = c2*mai - s2*mbi;  // c2*m_a + s2*conj(m_b)
      const float nbr = c2*mbr - s2*mar, nbi = c2*mbi + s2*mai;  // c2*m_b - s2*conj(m_a)
      m1s[id] = make_float4(c3*nar + s3*nai, c3*nai - s3*nar,    // e3*n_a
                            c3*nbr + s3*nbi, c3*nbi - s3*nbr);   // e3*n_b
    } else {
      // U = RZ(a5) RY(a4)
      float s4,c4,s5,c5;
      sincosf(0.5f*a[44+q], &s4,&c4);
      sincosf(0.5f*a[55+q], &s5,&c5);
      m2s[id] = make_float4(c5*c4, -s5*c4, -c5*s4, s5*s4);
    }
  }
  __syncthreads();

  // V[c][t] = m2[c][t-1] * m1[c][t]  (SU2 product)
  if (tid < NC * 10) {
    const int c = tid / 10, tt = tid - c * 10, t = tt + 1;
    const float4 A = m2s[c*NQ + t - 1];  // (p,q2)
    const float4 B = m1s[c*NQ + t];      // (a,b)
    const float pr_=A.x, pi_=A.y, qr_=A.z, qi_=A.w;
    const float ar_=B.x, ai_=B.y, br_=B.z, bi_=B.w;
    // V.a = p*a - q*conj(b) ; V.b = p*b + q*conj(a)
    v1s[c*10 + tt] = make_float4(
      (pr_*ar_ - pi_*ai_) - (qr_*br_ + qi_*bi_),
      (pr_*ai_ + pi_*ar_) - (qi_*br_ - qr_*bi_),
      (pr_*br_ - pi_*bi_) + (qr_*ar_ + qi_*ai_),
      (pr_*bi_ + pi_*br_) + (qi_*ar_ - qr_*ai_));
  }
  __syncthreads();

  // amp bits: [1:0]=reg (b0<->q0, b1<->q10); [7:2]=lane bits 0..5 <->
  // q9,q8,q7,q3,q2,q1 ; [10:8]=wave bits 0..2 <-> q6,q5,q4
  float sr[4], si[4];
#pragma unroll
  for (int i = 0; i < 4; ++i) { sr[i] = 0.f; si[i] = 0.f; }
  if (tid == 0) sr[0] = 1.f;

  int par = 0;
  for (int c = 0; c < NC; ++c) {
    const float4* M1 = &m1s[c * NQ];
    const float4* VF = &v1s[c * 10];
    { // e0: 1q(q0), reg bit0
      const float4 U = M1[0];
      apply2f(sr[0], si[0], sr[1], si[1], U);
      apply2f(sr[2], si[2], sr[3], si[3], U);
    }
    g_pl32_regsel(sr, si, M1[1], VF[0], lane);                      // e1: F(1|0)
    g_pl16(sr, si, (lane & 32) ? VF[1] : M1[2], lane);              // e2: F(2|1)
    g_shfl<8>(sr, si, (lane & 16) ? VF[2] : M1[3], lane);           // e3: F(3|2)
    g_wave<4>(sr, si, (lane & 8) ? VF[3] : M1[4],
              par ? ex1 : ex0, wave, lane); par ^= 1;               // e4: F(4|3)
    g_wave<2>(sr, si, (wave & 4) ? VF[4] : M1[5],
              par ? ex1 : ex0, wave, lane); par ^= 1;               // e5: F(5|4)
    g_wave<1>(sr, si, (wave & 2) ? VF[5] : M1[6],
              par ? ex1 : ex0, wave, lane); par ^= 1;               // e6: F(6|5)
    g_shfl<4>(sr, si, (wave & 1) ? VF[6] : M1[7], lane);            // e7: F(7|6)
    g_dpp<0x4E,2>(sr, si, (lane & 4) ? VF[7] : M1[8], lane);        // e8: F(8|7)
    g_dpp<0xB1,1>(sr, si, (lane & 2) ? VF[8] : M1[9], lane);        // e9: F(9|8)
    { // e10: F(10|9), target reg bit1, ctrl lane bit0
      const float4 U = (lane & 1) ? VF[9] : M1[10];
      apply2f(sr[0], si[0], sr[2], si[2], U);
      apply2f(sr[1], si[1], sr[3], si[3], U);
    }
    { // e11: C(10->0): ctrl reg bit1, target reg bit0 — pure registers
      const float4 U = m2s[c * NQ + 10];
      apply2f(sr[2], si[2], sr[3], si[3], U);
    }
  }

  // ---- expectations ----
  float2* eb = par ? ex1 : ex0;
  const int base = (wave << 6) | lane;
#pragma unroll
  for (int i = 0; i < 4; ++i) eb[(i << 9) | base] = make_float2(sr[i], si[i]);
  __syncthreads();
  const int pb4 = ((wave ^ 4) << 6) | lane;
  const int pb2 = ((wave ^ 2) << 6) | lane;
  const int pb1 = ((wave ^ 1) << 6) | lane;
  float xq4 = 0.f, xq5 = 0.f, xq6 = 0.f;
#pragma unroll
  for (int i = 0; i < 4; ++i) {
    const float2 p4 = eb[(i << 9) | pb4];
    const float2 p2 = eb[(i << 9) | pb2];
    const float2 p1 = eb[(i << 9) | pb1];
    xq4 += sr[i] * p4.x + si[i] * p4.y;
    xq5 += sr[i] * p2.x + si[i] * p2.y;
    xq6 += sr[i] * p1.x + si[i] * p1.y;
  }
  float mg[4];
#pragma unroll
  for (int i = 0; i < 4; ++i) mg[i] = sr[i]*sr[i] + si[i]*si[i];
  const float ztot = (mg[0] + mg[1]) + (mg[2] + mg[3]);
  const float zq0  = (mg[0] - mg[1]) + (mg[2] - mg[3]);
  const float zq10 = (mg[0] + mg[1]) - (mg[2] + mg[3]);
  float xq0=0.f, xq10=0.f, xq9=0.f, xq8=0.f, xq7=0.f, xq3=0.f, xq2=0.f, xq1=0.f;
#pragma unroll
  for (int i = 0; i < 4; ++i) {
    xq0  += sr[i]*sr[i^1] + si[i]*si[i^1];
    xq10 += sr[i]*sr[i^2] + si[i]*si[i^2];
    xq9 += sr[i]*dppx<0xB1>(sr[i]) + si[i]*dppx<0xB1>(si[i]);
    xq8 += sr[i]*dppx<0x4E>(sr[i]) + si[i]*dppx<0x4E>(si[i]);
    xq7 += sr[i]*__shfl_xor(sr[i],4,64) + si[i]*__shfl_xor(si[i],4,64);
    xq3 += sr[i]*__shfl_xor(sr[i],8,64) + si[i]*__shfl_xor(si[i],8,64);
    xq2 += sr[i]*plp16(sr[i],lane) + si[i]*plp16(si[i],lane);
    xq1 += sr[i]*plp32(sr[i],lane) + si[i]*plp32(si[i],lane);
  }

  float v[22];
  v[0]=xq0; v[1]=xq1; v[2]=xq2; v[3]=xq3; v[4]=xq4; v[5]=xq5; v[6]=xq6;
  v[7]=xq7; v[8]=xq8; v[9]=xq9; v[10]=xq10;
  v[11] = zq0;
  v[12] = (lane & 32) ? -ztot : ztot;   // Z q1
  v[13] = (lane & 16) ? -ztot : ztot;   // Z q2
  v[14] = (lane & 8)  ? -ztot : ztot;   // Z q3
  v[15] = (wave & 4)  ? -ztot : ztot;   // Z q4
  v[16] = (wave & 2)  ? -ztot : ztot;   // Z q5
  v[17] = (wave & 1)  ? -ztot : ztot;   // Z q6
  v[18] = (lane & 4)  ? -ztot : ztot;   // Z q7
  v[19] = (lane & 2)  ? -ztot : ztot;   // Z q8
  v[20] = (lane & 1)  ? -ztot : ztot;   // Z q9
  v[21] = zq10;

  // reduction: DPP quad levels, pack 4/reg, shfl xor4/8, permlane 16/32
#pragma unroll
  for (int k = 0; k < 22; ++k) {
    v[k] += dppx<0xB1>(v[k]);
    v[k] += dppx<0x4E>(v[k]);
  }
  const int q4l = lane & 3;
  float wv[6];
#pragma unroll
  for (int p = 0; p < 5; ++p)
    wv[p] = q4l == 0 ? v[4*p] : (q4l == 1 ? v[4*p+1] : (q4l == 2 ? v[4*p+2] : v[4*p+3]));
  wv[5] = q4l == 0 ? v[20] : (q4l == 1 ? v[21] : 0.f);
#pragma unroll
  for (int p = 0; p < 6; ++p) {
    wv[p] += __shfl_xor(wv[p], 4, 64);
    wv[p] += __shfl_xor(wv[p], 8, 64);
    wv[p] = plsum16(wv[p]);
    wv[p] = plsum32(wv[p]);
  }
  if (lane < 4) {
#pragma unroll
    for (int p = 0; p < 6; ++p) red[wave][4*p + lane] = wv[p];
  }
  __syncthreads();
  if (tid < 22) {
    float s = 0.f;
#pragma unroll
    for (int w8 = 0; w8 < 8; ++w8) s += red[w8][tid];
    out[bidx * 22 + tid] = s;
  }
}

extern "C" void kernel_launch(void* const* d_in, const int* in_sizes, int n_in,
                              void* d_out, int out_size, void* d_ws, size_t ws_size,
                              hipStream_t stream) {
  (void)n_in; (void)d_ws; (void)ws_size; (void)out_size;
  const float* x = (const float*)d_in[0];
  const float* W = (const float*)d_in[1];
  const float* b = (const float*)d_in[2];
  float* out = (float*)d_out;
  const int batch = in_sizes[0] / NQ;
  qsim_kernel<<<batch, BLOCK, 0, stream>>>(x, W, b, out);
}

// Round 6
// 21.587 us; speedup vs baseline: 1.8439x; 1.2289x over previous
//
#include <hip/hip_runtime.h>

#define NQ 11
#define NC 3
#define NANG (NC * 66)
#define BLOCK 512

typedef float f2 __attribute__((ext_vector_type(2)));

__device__ __forceinline__ f2 swp(f2 v) { return __builtin_shufflevector(v, v, 1, 0); }

// DPP quad_perm: 0xB1 = xor1, 0x4E = xor2
template<int CTRL>
__device__ __forceinline__ float dppx(float v) {
  return __int_as_float(__builtin_amdgcn_update_dpp(
      0, __float_as_int(v), CTRL, 0xF, 0xF, false));
}
template<int CTRL>
__device__ __forceinline__ f2 dpp2(f2 v) {
  f2 r; r.x = dppx<CTRL>(v.x); r.y = dppx<CTRL>(v.y); return r;
}
__device__ __forceinline__ f2 shfl2(f2 v, int m) {
  f2 r; r.x = __shfl_xor(v.x, m, 64); r.y = __shfl_xor(v.y, m, 64); return r;
}
// partner value at lane^16 / lane^32 via gfx950 permlane swaps (VALU pipe)
__device__ __forceinline__ float plp16(float v, int lane) {
  auto r = __builtin_amdgcn_permlane16_swap(__float_as_int(v), __float_as_int(v), false, false);
  return __int_as_float((lane & 16) ? r[0] : r[1]);
}
__device__ __forceinline__ float plp32(float v, int lane) {
  auto r = __builtin_amdgcn_permlane32_swap(__float_as_int(v), __float_as_int(v), false, false);
  return __int_as_float((lane & 32) ? r[0] : r[1]);
}
__device__ __forceinline__ f2 plp16_2(f2 v, int lane) {
  f2 r; r.x = plp16(v.x, lane); r.y = plp16(v.y, lane); return r;
}
__device__ __forceinline__ f2 plp32_2(f2 v, int lane) {
  f2 r; r.x = plp32(v.x, lane); r.y = plp32(v.y, lane); return r;
}
__device__ __forceinline__ float plsum16(float v) {
  auto r = __builtin_amdgcn_permlane16_swap(__float_as_int(v), __float_as_int(v), false, false);
  return __int_as_float(r[0]) + __int_as_float(r[1]);
}
__device__ __forceinline__ float plsum32(float v) {
  auto r = __builtin_amdgcn_permlane32_swap(__float_as_int(v), __float_as_int(v), false, false);
  return __int_as_float(r[0]) + __int_as_float(r[1]);
}

// SU(2) matrix U = [[a, b], [-conj(b), conj(a)]] stored float4 (ar, ai, br, bi).
// Packed complex apply to in-thread pair: (v0,v1) <- U (v0,v1)
__device__ __forceinline__ void apply2p(f2& v0, f2& v1, float4 U) {
  const f2 ai2 = {-U.y, U.y};
  const f2 bi2 = {-U.w, U.w};
  const f2 w0 = swp(v0), w1 = swp(v1);
  const f2 n0 =  U.x * v0 + ai2 * w0 + U.z * v1 + bi2 * w1;
  const f2 n1 = -U.z * v0 + bi2 * w0 + U.x * v1 - ai2 * w1;
  v0 = n0; v1 = n1;
}
// own/partner row apply: v <- row(hi) of U applied to (own=v, partner=p)
__device__ __forceinline__ void gpartp(f2& v, f2 p, float4 U, bool hi) {
  const f2 ai2 = hi ? f2{U.y, -U.y} : f2{-U.y, U.y};
  const float br = hi ? -U.z : U.z;
  const f2 bi2 = {-U.w, U.w};
  v = U.x * v + ai2 * swp(v) + br * p + bi2 * swp(p);
}

template<int M>
__device__ __forceinline__ void g_shfl(f2 (&s)[4], float4 U, int lane) {
  const bool hi = (lane & M) != 0;
#pragma unroll
  for (int i = 0; i < 4; ++i) gpartp(s[i], shfl2(s[i], M), U, hi);
}
template<int CTRL, int M>
__device__ __forceinline__ void g_dpp(f2 (&s)[4], float4 U, int lane) {
  const bool hi = (lane & M) != 0;
#pragma unroll
  for (int i = 0; i < 4; ++i) gpartp(s[i], dpp2<CTRL>(s[i]), U, hi);
}
__device__ __forceinline__ void g_pl16(f2 (&s)[4], float4 U, int lane) {
  const bool hi = (lane & 16) != 0;
#pragma unroll
  for (int i = 0; i < 4; ++i) gpartp(s[i], plp16_2(s[i], lane), U, hi);
}
// target lane bit 32; matrix per amp by reg bit0
__device__ __forceinline__ void g_pl32_regsel(f2 (&s)[4], float4 U0, float4 U1, int lane) {
  const bool hi = (lane & 32) != 0;
#pragma unroll
  for (int i = 0; i < 4; ++i)
    gpartp(s[i], plp32_2(s[i], lane), (i & 1) ? U1 : U0, hi);
}
// wave-bit gate via LDS exchange
template<int WVX>
__device__ __forceinline__ void g_wave(f2 (&s)[4], float4 U, f2* buf, int wave, int lane) {
  const int base = (wave << 6) | lane;
#pragma unroll
  for (int i = 0; i < 4; ++i) buf[(i << 9) | base] = s[i];
  __syncthreads();
  const int pbase = ((wave ^ WVX) << 6) | lane;
  const bool hi = (wave & WVX) != 0;
#pragma unroll
  for (int i = 0; i < 4; ++i) gpartp(s[i], buf[(i << 9) | pbase], U, hi);
}

__global__ __launch_bounds__(BLOCK) void qsim_kernel(
    const float* __restrict__ x, const float* __restrict__ W,
    const float* __restrict__ bias, float* __restrict__ out) {
  const int bidx = blockIdx.x;
  const int tid = threadIdx.x;
  const int lane = tid & 63, wave = tid >> 6;   // wave 0..7

  __shared__ float xs[NQ];
  __shared__ float ang[NANG];
  __shared__ float4 m1s[NC * NQ];   // fused 1q matrices (SU2)
  __shared__ float4 m2s[NC * NQ];   // fused controlled matrices (SU2)
  __shared__ float4 v1s[NC * 10];   // V[t] = m2[t-1] * m1[t], t=1..10
  __shared__ f2 ex0[2048];
  __shared__ f2 ex1[2048];
  __shared__ float red[8][24];

  if (tid < NQ) xs[tid] = x[bidx * NQ + tid];
  __syncthreads();

  if (tid < NANG) {
    const int c = tid / 66, o = tid - c * 66;
    const float* wr = W + (c * 66 + o) * NQ;
    float s = bias[c * 66 + o];
#pragma unroll
    for (int i = 0; i < NQ; ++i) s += wr[i] * xs[i];
    ang[tid] = s;
  }
  __syncthreads();

  if (tid < 2 * NC * NQ) {
    const int kind = tid / (NC * NQ);
    const int id = tid - kind * (NC * NQ);
    const int c = id / NQ, q = id - c * NQ;
    const float* a = ang + c * 66;
    if (kind == 0) {
      // U = RZ(a3) RY(a2) RZ(a1) RY(a0), SU2 form (a,b)
      float s0,c0,s1,c1,s2,c2,s3,c3;
      sincosf(0.5f*a[q],      &s0,&c0);
      sincosf(0.5f*a[11+q],   &s1,&c1);
      sincosf(0.5f*a[22+q],   &s2,&c2);
      sincosf(0.5f*a[33+q],   &s3,&c3);
      const float mar = c1*c0, mai = -s1*c0;
      const float mbr = -c1*s0, mbi = s1*s0;
      const float nar = c2*mar + s2*mbr, nai = c2*mai - s2*mbi;
      const float nbr = c2*mbr - s2*mar, nbi = c2*mbi + s2*mai;
      m1s[id] = make_float4(c3*nar + s3*nai, c3*nai - s3*nar,
                            c3*nbr + s3*nbi, c3*nbi - s3*nbr);
    } else {
      // U = RZ(a5) RY(a4)
      float s4,c4,s5,c5;
      sincosf(0.5f*a[44+q], &s4,&c4);
      sincosf(0.5f*a[55+q], &s5,&c5);
      m2s[id] = make_float4(c5*c4, -s5*c4, -c5*s4, s5*s4);
    }
  }
  __syncthreads();

  // V[c][t] = m2[c][t-1] * m1[c][t]  (SU2 product)
  if (tid < NC * 10) {
    const int c = tid / 10, tt = tid - c * 10, t = tt + 1;
    const float4 A = m2s[c*NQ + t - 1];
    const float4 B = m1s[c*NQ + t];
    const float pr_=A.x, pi_=A.y, qr_=A.z, qi_=A.w;
    const float ar_=B.x, ai_=B.y, br_=B.z, bi_=B.w;
    v1s[c*10 + tt] = make_float4(
      (pr_*ar_ - pi_*ai_) - (qr_*br_ + qi_*bi_),
      (pr_*ai_ + pi_*ar_) - (qi_*br_ - qr_*bi_),
      (pr_*br_ - pi_*bi_) + (qr_*ar_ + qi_*ai_),
      (pr_*bi_ + pi_*br_) + (qi_*ar_ - qr_*ai_));
  }
  __syncthreads();

  // amp bits: [1:0]=reg (b0<->q0, b1<->q10); [7:2]=lane bits <->
  // q9,q8,q7,q3,q2,q1 ; [10:8]=wave bits <-> q6,q5,q4
  f2 s[4];
#pragma unroll
  for (int i = 0; i < 4; ++i) s[i] = f2{0.f, 0.f};
  if (tid == 0) s[0].x = 1.f;

  int par = 0;
  for (int c = 0; c < NC; ++c) {
    const float4* M1 = &m1s[c * NQ];
    const float4* VF = &v1s[c * 10];
    { // e0: 1q(q0), reg bit0
      const float4 U = M1[0];
      apply2p(s[0], s[1], U);
      apply2p(s[2], s[3], U);
    }
    g_pl32_regsel(s, M1[1], VF[0], lane);                              // e1: F(1|0)
    g_pl16(s, *((lane & 32) ? &VF[1] : &M1[2]), lane);                 // e2: F(2|1)
    g_shfl<8>(s, *((lane & 16) ? &VF[2] : &M1[3]), lane);              // e3: F(3|2)
    g_wave<4>(s, *((lane & 8) ? &VF[3] : &M1[4]),
              par ? ex1 : ex0, wave, lane); par ^= 1;                  // e4: F(4|3)
    g_wave<2>(s, *((wave & 4) ? &VF[4] : &M1[5]),
              par ? ex1 : ex0, wave, lane); par ^= 1;                  // e5: F(5|4)
    g_wave<1>(s, *((wave & 2) ? &VF[5] : &M1[6]),
              par ? ex1 : ex0, wave, lane); par ^= 1;                  // e6: F(6|5)
    g_shfl<4>(s, *((wave & 1) ? &VF[6] : &M1[7]), lane);               // e7: F(7|6)
    g_dpp<0x4E,2>(s, *((lane & 4) ? &VF[7] : &M1[8]), lane);           // e8: F(8|7)
    g_dpp<0xB1,1>(s, *((lane & 2) ? &VF[8] : &M1[9]), lane);           // e9: F(9|8)
    { // e10: F(10|9), target reg bit1, ctrl lane bit0
      const float4 U = *((lane & 1) ? &VF[9] : &M1[10]);
      apply2p(s[0], s[2], U);
      apply2p(s[1], s[3], U);
    }
    { // e11: C(10->0): ctrl reg bit1, target reg bit0 — pure registers
      const float4 U = m2s[c * NQ + 10];
      apply2p(s[2], s[3], U);
    }
  }

  // ---- expectations ----
  f2* eb = par ? ex1 : ex0;
  const int base = (wave << 6) | lane;
#pragma unroll
  for (int i = 0; i < 4; ++i) eb[(i << 9) | base] = s[i];
  __syncthreads();
  const int pb4 = ((wave ^ 4) << 6) | lane;
  const int pb2 = ((wave ^ 2) << 6) | lane;
  const int pb1 = ((wave ^ 1) << 6) | lane;
  f2 aq4 = {0,0}, aq5 = {0,0}, aq6 = {0,0};
#pragma unroll
  for (int i = 0; i < 4; ++i) {
    aq4 += s[i] * eb[(i << 9) | pb4];
    aq5 += s[i] * eb[(i << 9) | pb2];
    aq6 += s[i] * eb[(i << 9) | pb1];
  }
  f2 mg[4];
#pragma unroll
  for (int i = 0; i < 4; ++i) mg[i] = s[i] * s[i];
  const f2 ztv  = (mg[0] + mg[1]) + (mg[2] + mg[3]);
  const f2 z0v  = (mg[0] - mg[1]) + (mg[2] - mg[3]);
  const f2 z10v = (mg[0] + mg[1]) - (mg[2] + mg[3]);
  f2 aq0={0,0}, aq10={0,0}, aq9={0,0}, aq8={0,0}, aq7={0,0}, aq3={0,0}, aq2={0,0}, aq1={0,0};
#pragma unroll
  for (int i = 0; i < 4; ++i) {
    aq0  += s[i] * s[i ^ 1];
    aq10 += s[i] * s[i ^ 2];
    aq9  += s[i] * dpp2<0xB1>(s[i]);
    aq8  += s[i] * dpp2<0x4E>(s[i]);
    aq7  += s[i] * shfl2(s[i], 4);
    aq3  += s[i] * shfl2(s[i], 8);
    aq2  += s[i] * plp16_2(s[i], lane);
    aq1  += s[i] * plp32_2(s[i], lane);
  }
  const float ztot = ztv.x + ztv.y;

  float v[22];
  v[0]=aq0.x+aq0.y; v[1]=aq1.x+aq1.y; v[2]=aq2.x+aq2.y; v[3]=aq3.x+aq3.y;
  v[4]=aq4.x+aq4.y; v[5]=aq5.x+aq5.y; v[6]=aq6.x+aq6.y;
  v[7]=aq7.x+aq7.y; v[8]=aq8.x+aq8.y; v[9]=aq9.x+aq9.y; v[10]=aq10.x+aq10.y;
  v[11] = z0v.x + z0v.y;
  v[12] = (lane & 32) ? -ztot : ztot;   // Z q1
  v[13] = (lane & 16) ? -ztot : ztot;   // Z q2
  v[14] = (lane & 8)  ? -ztot : ztot;   // Z q3
  v[15] = (wave & 4)  ? -ztot : ztot;   // Z q4
  v[16] = (wave & 2)  ? -ztot : ztot;   // Z q5
  v[17] = (wave & 1)  ? -ztot : ztot;   // Z q6
  v[18] = (lane & 4)  ? -ztot : ztot;   // Z q7
  v[19] = (lane & 2)  ? -ztot : ztot;   // Z q8
  v[20] = (lane & 1)  ? -ztot : ztot;   // Z q9
  v[21] = z10v.x + z10v.y;

  // reduction: DPP quad levels, pack 4/reg, shfl xor4/8, permlane 16/32
#pragma unroll
  for (int k = 0; k < 22; ++k) {
    v[k] += dppx<0xB1>(v[k]);
    v[k] += dppx<0x4E>(v[k]);
  }
  const int q4l = lane & 3;
  float wv[6];
#pragma unroll
  for (int p = 0; p < 5; ++p)
    wv[p] = q4l == 0 ? v[4*p] : (q4l == 1 ? v[4*p+1] : (q4l == 2 ? v[4*p+2] : v[4*p+3]));
  wv[5] = q4l == 0 ? v[20] : (q4l == 1 ? v[21] : 0.f);
#pragma unroll
  for (int p = 0; p < 6; ++p) {
    wv[p] += __shfl_xor(wv[p], 4, 64);
    wv[p] += __shfl_xor(wv[p], 8, 64);
    wv[p] = plsum16(wv[p]);
    wv[p] = plsum32(wv[p]);
  }
  if (lane < 4) {
#pragma unroll
    for (int p = 0; p < 6; ++p) red[wave][4*p + lane] = wv[p];
  }
  __syncthreads();
  if (tid < 22) {
    float sacc = 0.f;
#pragma unroll
    for (int w8 = 0; w8 < 8; ++w8) sacc += red[w8][tid];
    out[bidx * 22 + tid] = sacc;
  }
}

extern "C" void kernel_launch(void* const* d_in, const int* in_sizes, int n_in,
                              void* d_out, int out_size, void* d_ws, size_t ws_size,
                              hipStream_t stream) {
  (void)n_in; (void)d_ws; (void)ws_size; (void)out_size;
  const float* x = (const float*)d_in[0];
  const float* W = (const float*)d_in[1];
  const float* b = (const float*)d_in[2];
  float* out = (float*)d_out;
  const int batch = in_sizes[0] / NQ;
  qsim_kernel<<<batch, BLOCK, 0, stream>>>(x, W, b, out);
}